// Round 3
// baseline (2136.085 us; speedup 1.0000x reference)
//
#include <hip/hip_runtime.h>
#include <hip/hip_bf16.h>

typedef __hip_bfloat16 bf16;

#define HW 65536   // 256*256

__device__ __forceinline__ float b2f(bf16 v){ return __bfloat162float(v); }
__device__ __forceinline__ bf16  f2b(float v){ return __float2bfloat16(v); }

// src layout [o=64][i=64][3][3] f32 -> dst [i][tap][o] f32
__global__ void transpose_w33(const float* __restrict__ src, float* __restrict__ dst){
  int i = blockIdx.x*256 + threadIdx.x;
  if (i >= 64*64*9) return;
  int e = i / 576; int r = i % 576; int t = r / 64; int c = r % 64;
  dst[i] = src[(c*64 + e)*9 + t];
}

// ---------------- lang head: log_softmax(relu(action@w_a1+b)@w_a2+b) ----------------
__global__ void lang_kernel(const float* __restrict__ action,
                            const float* __restrict__ w_a1, const float* __restrict__ b_a1,
                            const float* __restrict__ w_a2, const float* __restrict__ b_a2,
                            float* __restrict__ lang){
  int n = blockIdx.x; int t = threadIdx.x;   // 64 threads
  __shared__ float hid[64];
  __shared__ float logits[49];
  __shared__ float lse_sh;
  float acc = b_a1[t];
  for (int a = 0; a < 256; a++) acc += action[n*256+a] * w_a1[a*64+t];
  hid[t] = fmaxf(acc, 0.f);
  __syncthreads();
  if (t < 49){
    float l = b_a2[t];
    for (int j = 0; j < 64; j++) l += hid[j] * w_a2[j*49+t];
    logits[t] = l;
  }
  __syncthreads();
  if (t == 0){
    float m = -1e30f;
    for (int k = 0; k < 49; k++) m = fmaxf(m, logits[k]);
    float s = 0.f;
    for (int k = 0; k < 49; k++) s += __expf(logits[k]-m);
    lse_sh = m + __logf(s);
  }
  __syncthreads();
  if (t < 49) lang[n*49+t] = logits[t] - lse_sh;
}

// ---------------- maxpool 2x2 + 1x1 conv 32->64 + relu ----------------
__global__ __launch_bounds__(256) void pool_in_kernel(
    const float* __restrict__ sm,
    const float* __restrict__ w_in, const float* __restrict__ b_in,
    float* __restrict__ x, bf16* __restrict__ h1){
  int p = blockIdx.x*256 + threadIdx.x;
  int n = p >> 16; int ij = p & 65535; int i = ij >> 8; int j = ij & 255;
  float xv[32];
  #pragma unroll
  for (int d = 0; d < 32; d++){
    long base = ((long)(n*32 + d)*512 + 2*i)*512 + 2*j;  // even element index
    float2 p0 = *reinterpret_cast<const float2*>(sm + base);
    float2 p1 = *reinterpret_cast<const float2*>(sm + base + 512);
    float v = fmaxf(fmaxf(p0.x, p0.y), fmaxf(p1.x, p1.y));
    xv[d] = v;
    x[(long)(n*32 + d)*HW + ij] = v;
  }
  #pragma unroll 4
  for (int c = 0; c < 64; c++){
    float acc = b_in[c];
    #pragma unroll
    for (int d = 0; d < 32; d++) acc += xv[d]*w_in[c*32+d];
    h1[(long)(n*64 + c)*HW + ij] = f2b(fmaxf(acc, 0.f));
  }
}

// ---------------- 3x3 conv 64->64 + relu, dilation DIL, pad DIL ----------------
template<int DIL>
__global__ __launch_bounds__(256) void conv3x3_kernel(
    const bf16* __restrict__ hin,
    const float* __restrict__ wt,      // [e][tap][c] f32
    const float* __restrict__ bias,
    bf16* __restrict__ hout){
  constexpr int R = 16 + 2*DIL, C = 16 + 2*DIL;
  __shared__ bf16 tile[64*R*C];
  int b = blockIdx.x;
  int n = b >> 8; int tb = b & 255; int ty = tb >> 4; int tx = tb & 15;
  int i0 = ty*16, j0 = tx*16;
  int tid = threadIdx.x;
  for (int idx = tid; idx < 64*R*C; idx += 256){
    int e = idx / (R*C); int rr = idx % (R*C); int r = rr / C; int c = rr % C;
    int gi = i0 - DIL + r, gj = j0 - DIL + c;
    bf16 v = f2b(0.f);
    if (gi >= 0 && gi < 256 && gj >= 0 && gj < 256)
      v = hin[(long)(n*64 + e)*HW + gi*256 + gj];
    tile[idx] = v;
  }
  __syncthreads();
  int row = tid >> 4, col = tid & 15;
  float acc[64];
  #pragma unroll
  for (int c = 0; c < 64; c++) acc[c] = bias[c];
  for (int e = 0; e < 64; e++){
    float tv[9];
    #pragma unroll
    for (int ku = 0; ku < 3; ku++)
      #pragma unroll
      for (int kv = 0; kv < 3; kv++)
        tv[ku*3+kv] = b2f(tile[e*(R*C) + (row + ku*DIL)*C + (col + kv*DIL)]);
    #pragma unroll
    for (int t = 0; t < 9; t++){
      const float* wrow = wt + (e*9 + t)*64;
      #pragma unroll
      for (int c = 0; c < 64; c++) acc[c] += tv[t]*wrow[c];
    }
  }
  int i = i0 + row, j = j0 + col;
  long obase = (long)(n*64)*HW + i*256 + j;
  #pragma unroll
  for (int c = 0; c < 64; c++)
    hout[obase + (long)c*HW] = f2b(fmaxf(acc[c], 0.f));
}

// ---------------- residual 1x1 64->32, 1x1 32->49 + lang, fused log_softmax ----------------
__global__ __launch_bounds__(256) void out_motion_kernel(
    const bf16* __restrict__ h3, const float* __restrict__ x,
    const float* __restrict__ w_out, const float* __restrict__ b_out,
    const float* __restrict__ w_k, const float* __restrict__ b_k,
    const float* __restrict__ lang, float* __restrict__ lk){
  int p = blockIdx.x*256 + threadIdx.x;
  int n = p >> 16; int ij = p & 65535;
  float hv[64];
  #pragma unroll
  for (int e = 0; e < 64; e++) hv[e] = b2f(h3[(long)(n*64+e)*HW + ij]);
  float o[32];
  #pragma unroll 4
  for (int d = 0; d < 32; d++){
    float acc = b_out[d];
    #pragma unroll
    for (int e = 0; e < 64; e++) acc += hv[e]*w_out[d*64+e];
    o[d] = x[(long)(n*32+d)*HW + ij] + acc;
  }
  float lg[49]; float m = -1e30f;
  #pragma unroll 7
  for (int k = 0; k < 49; k++){
    float acc = b_k[k] + lang[n*49+k];
    #pragma unroll
    for (int d = 0; d < 32; d++) acc += o[d]*w_k[k*32+d];
    lg[k] = acc; m = fmaxf(m, acc);
  }
  float s = 0.f;
  #pragma unroll
  for (int k = 0; k < 49; k++) s += __expf(lg[k]-m);
  float lse = m + __logf(s);
  #pragma unroll
  for (int k = 0; k < 49; k++) lk[(long)(n*49+k)*HW + ij] = lg[k] - lse;
}

// ---------------- 7x7 gather logsumexp (f32 output!) ----------------
__global__ __launch_bounds__(256) void gather_lse_kernel(
    const float* __restrict__ lb, const float* __restrict__ lk, float* __restrict__ out){
  int p = blockIdx.x*256 + threadIdx.x;
  int n = p >> 16; int ij = p & 65535; int i = ij >> 8; int j = ij & 255;
  const float* lkn = lk + (long)n*49*HW;
  float v[49]; float m = -1e30f;
  #pragma unroll
  for (int ki = 0; ki < 7; ki++){
    int h = i + 3 - ki;
    bool hok = (h >= 0 && h < 256);
    #pragma unroll
    for (int kj = 0; kj < 7; kj++){
      int w = j + 3 - kj;
      float val = -1e30f;
      if (hok && w >= 0 && w < 256){
        int q = h*256 + w;
        val = lb[n*HW + q] + lkn[(ki*7+kj)*HW + q];
      }
      v[ki*7+kj] = val; m = fmaxf(m, val);
    }
  }
  float s = 0.f;
  #pragma unroll
  for (int t = 0; t < 49; t++) s += __expf(v[t]-m);
  out[p] = m + __logf(s);
}

// ---------------- launch ----------------
// ws layout (bytes):
//   x    f32  [8][32][65536]  @ 0            (67,108,864)
//   h1   bf16 [8][64][65536]  @  67,108,864  (67,108,864)
//   h2   bf16 [8][64][65536]  @ 134,217,728  (67,108,864)  -- dead after conv<1>
//   lk   f32  [8][49][65536]  @ 134,217,728  (102,760,448) -- overlaps dead h2
//   lang f32  [8][49]         @ 236,978,176  (1,792)
//   wt3  f32  [64][9][64]     @ 236,979,968  (147,456)
//   wt1  f32  [64][9][64]     @ 237,127,424  (147,456)
// total required: ~237.3 MB
extern "C" void kernel_launch(void* const* d_in, const int* in_sizes, int n_in,
                              void* d_out, int out_size, void* d_ws, size_t ws_size,
                              hipStream_t stream) {
  (void)in_sizes; (void)n_in; (void)out_size; (void)ws_size;
  const float* lb    = (const float*)d_in[0];
  const float* sm    = (const float*)d_in[1];
  const float* act   = (const float*)d_in[2];
  const float* w_in  = (const float*)d_in[3];
  const float* b_in  = (const float*)d_in[4];
  const float* w_d3  = (const float*)d_in[5];
  const float* b_d3  = (const float*)d_in[6];
  const float* w_d1  = (const float*)d_in[7];
  const float* b_d1  = (const float*)d_in[8];
  const float* w_out = (const float*)d_in[9];
  const float* b_out = (const float*)d_in[10];
  const float* w_k   = (const float*)d_in[11];
  const float* b_k   = (const float*)d_in[12];
  const float* w_a1  = (const float*)d_in[13];
  const float* b_a1  = (const float*)d_in[14];
  const float* w_a2  = (const float*)d_in[15];
  const float* b_a2  = (const float*)d_in[16];
  float* out = (float*)d_out;

  char* ws = (char*)d_ws;
  float* x    = (float*)(ws + 0);
  bf16*  h1   = (bf16*) (ws + 67108864);
  bf16*  h2   = (bf16*) (ws + 134217728);
  float* lk   = (float*)(ws + 134217728);
  float* lang = (float*)(ws + 236978176);
  float* wt3  = (float*)(ws + 236979968);
  float* wt1  = (float*)(ws + 237127424);

  transpose_w33<<<144, 256, 0, stream>>>(w_d3, wt3);
  transpose_w33<<<144, 256, 0, stream>>>(w_d1, wt1);

  lang_kernel<<<8, 64, 0, stream>>>(act, w_a1, b_a1, w_a2, b_a2, lang);

  pool_in_kernel<<<2048, 256, 0, stream>>>(sm, w_in, b_in, x, h1);
  conv3x3_kernel<3><<<2048, 256, 0, stream>>>(h1, wt3, b_d3, h2);
  conv3x3_kernel<1><<<2048, 256, 0, stream>>>(h2, wt1, b_d1, h1);
  out_motion_kernel<<<2048, 256, 0, stream>>>(h1, x, w_out, b_out,
                                              w_k, b_k, lang, lk);
  gather_lse_kernel<<<2048, 256, 0, stream>>>(lb, lk, out);
}

// Round 4
// 719.101 us; speedup vs baseline: 2.9705x; 2.9705x over previous
//
#include <hip/hip_runtime.h>
#include <hip/hip_bf16.h>

typedef __hip_bfloat16 bf16;
typedef __attribute__((ext_vector_type(8)))  short  short8;
typedef __attribute__((ext_vector_type(16))) float  floatx16;

#define HW 65536   // 256*256

__device__ __forceinline__ float b2f(bf16 v){ return __bfloat162float(v); }
__device__ __forceinline__ bf16  f2b(float v){ return __float2bfloat16(v); }
__device__ __forceinline__ unsigned short f2bu(float v){
  union { bf16 h; unsigned short u; } cv; cv.h = __float2bfloat16(v); return cv.u;
}
__device__ __forceinline__ float bu2f(unsigned short u){
  union { unsigned u; float f; } cv; cv.u = ((unsigned)u) << 16; return cv.f;
}

// ---- weight prep: w f32 [oc=64][ic=64][3][3] -> bf16 B-fragment granules
//      [t][ks][half][oc][8e]  (granule = 16B read by one lane)
__global__ void prep_w33(const float* __restrict__ w, bf16* __restrict__ wb){
  int i = blockIdx.x*256 + threadIdx.x;
  if (i >= 36864) return;
  int j    = i & 7;
  int gran = i >> 3;
  int oc   = gran & 63;
  int rest = gran >> 6;          // (t*4+ks)*2+half
  int half = rest & 1;
  int ks   = (rest >> 1) & 3;
  int t    = rest >> 3;
  int e  = ks*16 + half*8 + j;
  int ki = t / 3, kj = t - ki*3;
  wb[i] = f2b(w[(oc*64 + e)*9 + ki*3 + kj]);
}

// ---- lang head ----
__global__ void lang_kernel(const float* __restrict__ action,
                            const float* __restrict__ w_a1, const float* __restrict__ b_a1,
                            const float* __restrict__ w_a2, const float* __restrict__ b_a2,
                            float* __restrict__ lang){
  int n = blockIdx.x; int t = threadIdx.x;   // 64 threads
  __shared__ float hid[64];
  __shared__ float logits[49];
  __shared__ float lse_sh;
  float acc = b_a1[t];
  for (int a = 0; a < 256; a++) acc += action[n*256+a] * w_a1[a*64+t];
  hid[t] = fmaxf(acc, 0.f);
  __syncthreads();
  if (t < 49){
    float l = b_a2[t];
    for (int j = 0; j < 64; j++) l += hid[j] * w_a2[j*49+t];
    logits[t] = l;
  }
  __syncthreads();
  if (t == 0){
    float m = -1e30f;
    for (int k = 0; k < 49; k++) m = fmaxf(m, logits[k]);
    float s = 0.f;
    for (int k = 0; k < 49; k++) s += __expf(logits[k]-m);
    lse_sh = m + __logf(s);
  }
  __syncthreads();
  if (t < 49) lang[n*49+t] = logits[t] - lse_sh;
}

// ---- maxpool 2x2 + 1x1 conv 32->64 + relu; x,h1 written NHWC ----
__global__ __launch_bounds__(256) void pool_in_kernel(
    const float* __restrict__ sm, const float* __restrict__ w_in,
    const float* __restrict__ b_in, float* __restrict__ x, bf16* __restrict__ h1){
  int p = blockIdx.x*256 + threadIdx.x;
  int n = p >> 16; int ij = p & 65535; int i = ij >> 8; int j = ij & 255;
  const float* smn = sm + ((long)n << 23);   // n*32*512*512
  float xv[32];
  #pragma unroll
  for (int d = 0; d < 32; d++){
    long base = ((long)(d*512 + 2*i) << 9) + 2*j;
    float2 p0 = *reinterpret_cast<const float2*>(smn + base);
    float2 p1 = *reinterpret_cast<const float2*>(smn + base + 512);
    xv[d] = fmaxf(fmaxf(p0.x, p0.y), fmaxf(p1.x, p1.y));
  }
  float4* xo = reinterpret_cast<float4*>(x + ((long)p << 5));
  #pragma unroll
  for (int q = 0; q < 8; q++)
    xo[q] = make_float4(xv[4*q], xv[4*q+1], xv[4*q+2], xv[4*q+3]);
  unsigned ow[32];
  #pragma unroll 4
  for (int c = 0; c < 64; c += 2){
    float a0 = b_in[c], a1 = b_in[c+1];
    #pragma unroll
    for (int d = 0; d < 32; d++){
      a0 += xv[d]*w_in[c*32+d];
      a1 += xv[d]*w_in[(c+1)*32+d];
    }
    ow[c>>1] = ((unsigned)f2bu(fmaxf(a1,0.f)) << 16) | f2bu(fmaxf(a0,0.f));
  }
  uint4* ho = reinterpret_cast<uint4*>((char*)h1 + ((long)p << 7));
  #pragma unroll
  for (int q = 0; q < 8; q++)
    ho[q] = make_uint4(ow[4*q], ow[4*q+1], ow[4*q+2], ow[4*q+3]);
}

// ---- 3x3 conv 64->64 + relu via MFMA implicit GEMM; NHWC in/out ----
// block = 256 thr (4 waves), 16x16 spatial tile, M=256 pix, N=64 oc, K=576.
// wave w: m-tiles (w>>1)*4 .. +3 (32 pix each), n-tile w&1 (32 oc).
template<int DIL>
__global__ __launch_bounds__(256) void conv3x3_mfma(
    const bf16* __restrict__ hin, const bf16* __restrict__ wb,
    const float* __restrict__ bias, bf16* __restrict__ hout){
  constexpr int R = 16 + 2*DIL, C = 16 + 2*DIL, NPIX = R*C;
  __shared__ __align__(16) char tile[NPIX*128];   // [pix][64e] bf16, XOR-swizzled granules
  int b = blockIdx.x;
  int n = b >> 8; int tb = b & 255;
  int i0 = (tb >> 4) << 4, j0 = (tb & 15) << 4;
  int tid = threadIdx.x;
  const bf16* hn = hin + ((long)n << 22);  // n*HW*64
  for (int s = tid; s < NPIX*8; s += 256){
    int pix = s >> 3, g = s & 7;
    int r = pix / C, c = pix - r*C;
    int gi = i0 - DIL + r, gj = j0 - DIL + c;
    uint4 v = make_uint4(0u,0u,0u,0u);
    if (gi >= 0 && gi < 256 && gj >= 0 && gj < 256)
      v = *reinterpret_cast<const uint4*>(hn + (((long)((gi<<8) + gj)) << 6) + (g<<3));
    *reinterpret_cast<uint4*>(tile + pix*128 + ((g ^ (pix & 7)) << 4)) = v;
  }
  __syncthreads();
  int lane = tid & 63, wv = tid >> 6;
  int mg = wv >> 1, nt = wv & 1;
  int l31 = lane & 31, half = lane >> 5;
  floatx16 acc[4];
  #pragma unroll
  for (int mt = 0; mt < 4; mt++) acc[mt] = (floatx16)(0.0f);
  int prr[4], pcc[4];
  #pragma unroll
  for (int mt = 0; mt < 4; mt++){
    int pidx = (mg*4 + mt)*32 + l31;
    prr[mt] = pidx >> 4; pcc[mt] = pidx & 15;
  }
  const char* wbc = reinterpret_cast<const char*>(wb);
  for (int t = 0; t < 9; t++){
    int ki = t / 3, kj = t - ki*3;
    int pp[4];
    #pragma unroll
    for (int mt = 0; mt < 4; mt++)
      pp[mt] = (prr[mt] + ki*DIL)*C + (pcc[mt] + kj*DIL);
    #pragma unroll
    for (int ks = 0; ks < 4; ks++){
      short8 bfrag = *reinterpret_cast<const short8*>(
          wbc + ((((t*4 + ks)*2 + half)*64 + nt*32 + l31) << 4));
      #pragma unroll
      for (int mt = 0; mt < 4; mt++){
        short8 afrag = *reinterpret_cast<const short8*>(
            tile + pp[mt]*128 + (((ks*2 + half) ^ (pp[mt] & 7)) << 4));
        acc[mt] = __builtin_amdgcn_mfma_f32_32x32x16_bf16(afrag, bfrag, acc[mt], 0, 0, 0);
      }
    }
  }
  float bv = bias[nt*32 + l31];
  bf16* ho = hout + ((long)n << 22);
  #pragma unroll
  for (int mt = 0; mt < 4; mt++){
    #pragma unroll
    for (int reg = 0; reg < 16; reg++){
      int row = (reg & 3) + 8*(reg >> 2) + 4*half;     // C/D layout, 32x32 [m74/m101]
      int pidx = (mg*4 + mt)*32 + row;
      int pr = pidx >> 4, pc = pidx & 15;
      ho[(((long)(((i0+pr)<<8) + (j0+pc))) << 6) + nt*32 + l31] =
          f2b(fmaxf(acc[mt][reg] + bv, 0.f));
    }
  }
}

// ---- residual 1x1 64->32, 1x1 32->49 + lang, fused log_softmax; NHWC in, lk NCHW out
__global__ __launch_bounds__(256) void out_motion_kernel(
    const bf16* __restrict__ h3, const float* __restrict__ x,
    const float* __restrict__ w_out, const float* __restrict__ b_out,
    const float* __restrict__ w_k, const float* __restrict__ b_k,
    const float* __restrict__ lang, float* __restrict__ lk){
  int p = blockIdx.x*256 + threadIdx.x;
  int n = p >> 16; int ij = p & 65535;
  float hv[64];
  const uint4* hp = reinterpret_cast<const uint4*>((const char*)h3 + ((long)p << 7));
  #pragma unroll
  for (int q = 0; q < 8; q++){
    uint4 u = hp[q];
    unsigned uu[4] = {u.x, u.y, u.z, u.w};
    #pragma unroll
    for (int k = 0; k < 4; k++){
      hv[q*8 + 2*k]   = bu2f((unsigned short)(uu[k] & 0xffffu));
      hv[q*8 + 2*k+1] = bu2f((unsigned short)(uu[k] >> 16));
    }
  }
  float o[32];
  const float4* xp = reinterpret_cast<const float4*>(x + ((long)p << 5));
  #pragma unroll
  for (int q = 0; q < 8; q++){
    float4 tq = xp[q];
    o[4*q] = tq.x; o[4*q+1] = tq.y; o[4*q+2] = tq.z; o[4*q+3] = tq.w;
  }
  #pragma unroll 4
  for (int d = 0; d < 32; d++){
    float acc = b_out[d];
    #pragma unroll
    for (int e = 0; e < 64; e++) acc += hv[e]*w_out[d*64+e];
    o[d] += acc;
  }
  float lg[49]; float m = -1e30f;
  #pragma unroll 7
  for (int k = 0; k < 49; k++){
    float acc = b_k[k] + lang[n*49+k];
    #pragma unroll
    for (int d = 0; d < 32; d++) acc += o[d]*w_k[k*32+d];
    lg[k] = acc; m = fmaxf(m, acc);
  }
  float s = 0.f;
  #pragma unroll
  for (int k = 0; k < 49; k++) s += __expf(lg[k]-m);
  float lse = m + __logf(s);
  #pragma unroll
  for (int k = 0; k < 49; k++) lk[(long)n*49*HW + (long)k*HW + ij] = lg[k] - lse;
}

// ---- 7x7 gather logsumexp (f32 output) ----
__global__ __launch_bounds__(256) void gather_lse_kernel(
    const float* __restrict__ lb, const float* __restrict__ lk, float* __restrict__ out){
  int p = blockIdx.x*256 + threadIdx.x;
  int n = p >> 16; int ij = p & 65535; int i = ij >> 8; int j = ij & 255;
  const float* lkn = lk + (long)n*49*HW;
  float v[49]; float m = -1e30f;
  #pragma unroll
  for (int ki = 0; ki < 7; ki++){
    int h = i + 3 - ki;
    bool hok = (h >= 0 && h < 256);
    #pragma unroll
    for (int kj = 0; kj < 7; kj++){
      int w = j + 3 - kj;
      float val = -1e30f;
      if (hok && w >= 0 && w < 256){
        int q = h*256 + w;
        val = lb[n*HW + q] + lkn[(ki*7+kj)*HW + q];
      }
      v[ki*7+kj] = val; m = fmaxf(m, val);
    }
  }
  float s = 0.f;
  #pragma unroll
  for (int t = 0; t < 49; t++) s += __expf(v[t]-m);
  out[p] = m + __logf(s);
}

// ---- launch ----
// ws layout (bytes):
//   x    f32 NHWC [8][65536][32] @ 0            (67,108,864)
//   h1   bf16 NHWC [8][65536][64] @  67,108,864 (67,108,864)
//   h2   bf16 NHWC               @ 134,217,728  (67,108,864)  dead after conv<1>
//   lk   f32  [8][49][65536]     @ 134,217,728  (102,760,448) overlaps dead h2
//   lang f32  [8][49]            @ 236,978,176  (1,792)
//   wb3  bf16 granules           @ 236,979,968  (73,728)
//   wb1  bf16 granules           @ 237,053,696  (73,728)
extern "C" void kernel_launch(void* const* d_in, const int* in_sizes, int n_in,
                              void* d_out, int out_size, void* d_ws, size_t ws_size,
                              hipStream_t stream) {
  (void)in_sizes; (void)n_in; (void)out_size; (void)ws_size;
  const float* lb    = (const float*)d_in[0];
  const float* sm    = (const float*)d_in[1];
  const float* act   = (const float*)d_in[2];
  const float* w_in  = (const float*)d_in[3];
  const float* b_in  = (const float*)d_in[4];
  const float* w_d3  = (const float*)d_in[5];
  const float* b_d3  = (const float*)d_in[6];
  const float* w_d1  = (const float*)d_in[7];
  const float* b_d1  = (const float*)d_in[8];
  const float* w_out = (const float*)d_in[9];
  const float* b_out = (const float*)d_in[10];
  const float* w_k   = (const float*)d_in[11];
  const float* b_k   = (const float*)d_in[12];
  const float* w_a1  = (const float*)d_in[13];
  const float* b_a1  = (const float*)d_in[14];
  const float* w_a2  = (const float*)d_in[15];
  const float* b_a2  = (const float*)d_in[16];
  float* out = (float*)d_out;

  char* ws = (char*)d_ws;
  float* x    = (float*)(ws + 0);
  bf16*  h1   = (bf16*) (ws + 67108864);
  bf16*  h2   = (bf16*) (ws + 134217728);
  float* lk   = (float*)(ws + 134217728);
  float* lang = (float*)(ws + 236978176);
  bf16*  wb3  = (bf16*) (ws + 236979968);
  bf16*  wb1  = (bf16*) (ws + 237053696);

  prep_w33<<<144, 256, 0, stream>>>(w_d3, wb3);
  prep_w33<<<144, 256, 0, stream>>>(w_d1, wb1);
  lang_kernel<<<8, 64, 0, stream>>>(act, w_a1, b_a1, w_a2, b_a2, lang);

  pool_in_kernel<<<2048, 256, 0, stream>>>(sm, w_in, b_in, x, h1);
  conv3x3_mfma<3><<<2048, 256, 0, stream>>>(h1, wb3, b_d3, h2);
  conv3x3_mfma<1><<<2048, 256, 0, stream>>>(h2, wb1, b_d1, h1);
  out_motion_kernel<<<2048, 256, 0, stream>>>(h1, x, w_out, b_out,
                                              w_k, b_k, lang, lk);
  gather_lse_kernel<<<2048, 256, 0, stream>>>(lb, lk, out);
}